// Round 4
// baseline (64.184 us; speedup 1.0000x reference)
//
#include <hip/hip_runtime.h>

typedef unsigned short u16;
typedef __attribute__((ext_vector_type(8))) __bf16 bf16x8;
typedef __attribute__((ext_vector_type(4))) float f32x4;

#define GLOAD_LDS16(g, l)                                                                     \
  __builtin_amdgcn_global_load_lds((const __attribute__((address_space(1))) unsigned int*)(g), \
                                   (__attribute__((address_space(3))) unsigned int*)(l), 16, 0, 0)

static __device__ __forceinline__ u16 f2bf(float f) {
  unsigned int u = __float_as_uint(f);
  u += 0x7fffu + ((u >> 16) & 1u);   // round-to-nearest-even
  return (u16)(u >> 16);
}

// Constants for this problem instance
#define BATCH 32
#define NN 1024   // transform length (K and M of the GEMM)
#define MM 512    // columns (N of the GEMM)

// ---- kernel 1: DCT-III matrix, bf16, Mm[j][k] ----
__global__ void fill_m(u16* __restrict__ Mm) {
  int idx = blockIdx.x * 256 + threadIdx.x;
  if (idx >= NN * NN) return;
  int j = idx >> 10;
  int k = idx & (NN - 1);
  float v;
  if (k == 0) {
    v = 0.03125f;  // 1/sqrt(1024)
  } else {
    int p = (k * (2 * j + 1)) & 4095;              // phase mod 4096 (cos period)
    float ang = (float)p * 1.5339807878856412e-3f; // pi/2048
    v = 0.04419417382415922f * cosf(ang);          // sqrt(2/1024) * cos
  }
  Mm[idx] = f2bf(v);
}

// ---- kernel 2: fused 256x256x(BK=64) 8-wave GEMM, B transposed+converted in-kernel ----
// C[b] = Mm * X[b].  A = Mm[j][k] (bf16, k-contig);  X = x[b][k][c] (f32, c-contig).
// LDS: sA[2][256*64], sB[2][256*64] bf16, XOR-swizzled rows: 16B-chunk pc of row r
// holds data chunk pc ^ (r&7).  A staged via pre-swizzled-source global_load_lds
// (linear dest); B reg-staged: 8x float4 (4c x 8k per thread) -> cvt -> 4x
// transposing ds_write_b128 (k-contiguous per c-row, swizzled chunk).
// Tile t read from buf[t&1]; ALL staging for t+1 goes to buf[~t&1] during t.
// Per-tile phases q=0..3 (C-quadrant q), barrier at each phase end.
//   p0: issue 4 A-gloads(t+1) + 4 B-f32-loads half0;  B-frags(8 reads) + A-frags(q0) + 16 MFMA
//   p1: issue 4 B-f32-loads half1;                    A-frags(q1) + 16 MFMA
//   p2:                                               A-frags(q2) + 16 MFMA
//   p3: A-frags(q3) + 16 MFMA; cvt (compiler vmcnt drains B+A) + 4 ds_write_b128;
//       lgkmcnt(0); barrier  -> buf[nxt] fully ready for t+1
__global__ __launch_bounds__(512, 2) void gemm_idct(const u16* __restrict__ A,
                                                    const float* __restrict__ X,
                                                    float* __restrict__ C) {
  __shared__ __align__(16) u16 sA[2][16384];  // 64 KiB
  __shared__ __align__(16) u16 sB[2][16384];  // 64 KiB
  const int b  = blockIdx.z;
  const int tn = blockIdx.x;  // N tile (c), 0..1
  const int tm = blockIdx.y;  // M tile (j), 0..3
  const int t512 = threadIdx.x;
  const int wave = t512 >> 6, lane = t512 & 63;
  const int wm = wave >> 2, wn = wave & 3;   // 2 x 4 waves; per-wave out 128x64
  const int lhi = lane >> 4, llo = lane & 15;

  // --- A staging map (pre-swizzled source, linear gload_lds dest) ---
  const int srow = t512 >> 3;                  // row-in-slice 0..63
  const int sdc  = (t512 & 7) ^ (srow & 7);    // pre-swizzled data chunk
  const u16* gA = A + (size_t)(tm * 256 + srow) * NN + sdc * 8;
#define ISSUE_A(buf, q, tt) GLOAD_LDS16(gA + (size_t)(q) * 64 * NN + (tt) * 64, \
                                        &sA[buf][(q) * 4096 + t512 * 8])

  // --- B staging map: thread owns c-quad qi*4..qi*4+3 x k-rows kg*8..kg*8+7 ---
  const int qi = ((wave & 3) << 4) | llo;      // 0..63  (c-quad)
  const int kg = ((wave >> 2) << 2) | lhi;     // 0..7   (k-group)
  const float* gX = X + ((size_t)b * NN + kg * 8) * MM + tn * 256 + qi * 4;

  float bA[4][4], bB[4][4];  // [i: k-offset][j: c-offset]

  // ---- prologue: stage tile 0 into buf 0 ----
  {
#pragma unroll
    for (int q = 0; q < 4; ++q) ISSUE_A(0, q, 0);
#pragma unroll
    for (int i = 0; i < 4; ++i) {
      const float4 v = *(const float4*)(gX + (size_t)i * MM);
      bA[i][0] = v.x; bA[i][1] = v.y; bA[i][2] = v.z; bA[i][3] = v.w;
    }
#pragma unroll
    for (int i = 0; i < 4; ++i) {
      const float4 v = *(const float4*)(gX + (size_t)(4 + i) * MM);
      bB[i][0] = v.x; bB[i][1] = v.y; bB[i][2] = v.z; bB[i][3] = v.w;
    }
#pragma unroll
    for (int j = 0; j < 4; ++j) {
      const int c = qi * 4 + j;
      bf16x8 ov;
#pragma unroll
      for (int i = 0; i < 4; ++i) { ov[i] = (__bf16)bA[i][j]; ov[4 + i] = (__bf16)bB[i][j]; }
      *(bf16x8*)&sB[0][c * 64 + ((kg ^ (c & 7)) << 3)] = ov;
    }
    asm volatile("s_waitcnt vmcnt(0) lgkmcnt(0)" ::: "memory");
    __builtin_amdgcn_s_barrier();
    __builtin_amdgcn_sched_barrier(0);
  }

  f32x4 acc[8][4] = {};
  bf16x8 bfr[4][2];

  for (int t = 0; t < 16; ++t) {
    const int cur = t & 1, nxt = cur ^ 1;
    const u16* lA = &sA[cur][0];
    const u16* lB = &sB[cur][0];
    const float* gXt = gX + (size_t)(t + 1) * 64 * MM;
#pragma unroll
    for (int q = 0; q < 4; ++q) {
      // --- staging issues for tile t+1 (all into buf nxt / regs) ---
      if (q == 0) {
        if (t < 15) {
#pragma unroll
          for (int s = 0; s < 4; ++s) ISSUE_A(nxt, s, t + 1);
#pragma unroll
          for (int i = 0; i < 4; ++i) {
            const float4 v = *(const float4*)(gXt + (size_t)i * MM);
            bA[i][0] = v.x; bA[i][1] = v.y; bA[i][2] = v.z; bA[i][3] = v.w;
          }
        }
      } else if (q == 1) {
        if (t < 15) {
#pragma unroll
          for (int i = 0; i < 4; ++i) {
            const float4 v = *(const float4*)(gXt + (size_t)(4 + i) * MM);
            bB[i][0] = v.x; bB[i][1] = v.y; bB[i][2] = v.z; bB[i][3] = v.w;
          }
        }
      }
      // --- register fragments ---
      if (q == 0) {
#pragma unroll
        for (int nf = 0; nf < 4; ++nf)
#pragma unroll
          for (int ks = 0; ks < 2; ++ks) {
            const int rb = wn * 64 + nf * 16 + llo;
            bfr[nf][ks] = *(const bf16x8*)&lB[rb * 64 + ((((ks << 2) | lhi)) ^ (llo & 7)) * 8];
          }
      }
      bf16x8 af[2][2];
#pragma unroll
      for (int mf = 0; mf < 2; ++mf)
#pragma unroll
        for (int ks = 0; ks < 2; ++ks) {
          const int ra = q * 64 + wm * 32 + mf * 16 + llo;
          af[mf][ks] = *(const bf16x8*)&lA[ra * 64 + (((ks << 2) | lhi) ^ (llo & 7)) * 8];
        }
      // --- 16 MFMA (quadrant q x K=64); ks OUTER so same-acc distance = 8 ---
      __builtin_amdgcn_s_setprio(1);
#pragma unroll
      for (int ks = 0; ks < 2; ++ks)
#pragma unroll
        for (int mf = 0; mf < 2; ++mf)
#pragma unroll
          for (int nf = 0; nf < 4; ++nf)
            acc[(q << 1) | mf][nf] = __builtin_amdgcn_mfma_f32_16x16x32_bf16(
                af[mf][ks], bfr[nf][ks], acc[(q << 1) | mf][nf], 0, 0, 0);
      __builtin_amdgcn_s_setprio(0);
      // --- p3: convert + transposing LDS write of B(t+1), then tile-end sync ---
      if (q == 3) {
        if (t < 15) {
#pragma unroll
          for (int j = 0; j < 4; ++j) {
            const int c = qi * 4 + j;
            bf16x8 ov;
#pragma unroll
            for (int i = 0; i < 4; ++i) { ov[i] = (__bf16)bA[i][j]; ov[4 + i] = (__bf16)bB[i][j]; }
            *(bf16x8*)&sB[nxt][c * 64 + ((kg ^ (c & 7)) << 3)] = ov;
          }
        }
        asm volatile("s_waitcnt lgkmcnt(0)" ::: "memory");
      }
      __builtin_amdgcn_sched_barrier(0);
      __builtin_amdgcn_s_barrier();
      __builtin_amdgcn_sched_barrier(0);
    }
  }

  // ---- epilogue: C/D layout col=lane&15, row=(lane>>4)*4+reg ----
  float* Cb = C + (size_t)b * NN * MM;
  const int jbase = tm * 256 + wm * 32 + lhi * 4;
  const int cbase = tn * 256 + wn * 64 + llo;
#pragma unroll
  for (int q = 0; q < 4; ++q)
#pragma unroll
    for (int mf = 0; mf < 2; ++mf)
#pragma unroll
      for (int nf = 0; nf < 4; ++nf) {
        const int j = jbase + q * 64 + mf * 16;
        const int c = cbase + nf * 16;
#pragma unroll
        for (int r = 0; r < 4; ++r)
          Cb[(size_t)(j + r) * MM + c] = acc[(q << 1) | mf][nf][r];
      }
#undef ISSUE_A
}

extern "C" void kernel_launch(void* const* d_in, const int* in_sizes, int n_in,
                              void* d_out, int out_size, void* d_ws, size_t ws_size,
                              hipStream_t stream) {
  const float* x = (const float*)d_in[0];
  float* out = (float*)d_out;
  u16* Mm = (u16*)d_ws;  // NN*NN u16 = 2 MiB

  fill_m<<<dim3((NN * NN) / 256), dim3(256), 0, stream>>>(Mm);
  gemm_idct<<<dim3(MM / 256, NN / 256, BATCH), dim3(512), 0, stream>>>(Mm, x, out);
}

// Round 5
// 58.617 us; speedup vs baseline: 1.0950x; 1.0950x over previous
//
#include <hip/hip_runtime.h>

typedef unsigned short u16;
typedef __attribute__((ext_vector_type(8))) __bf16 bf16x8;
typedef __attribute__((ext_vector_type(4))) float f32x4;

#define GLOAD_LDS16(g, l)                                                                     \
  __builtin_amdgcn_global_load_lds((const __attribute__((address_space(1))) unsigned int*)(g), \
                                   (__attribute__((address_space(3))) unsigned int*)(l), 16, 0, 0)

static __device__ __forceinline__ u16 f2bf(float f) {
  unsigned int u = __float_as_uint(f);
  u += 0x7fffu + ((u >> 16) & 1u);   // round-to-nearest-even
  return (u16)(u >> 16);
}

// Constants for this problem instance
#define BATCH 32
#define NN 1024   // transform length (K and M of the GEMM)
#define MM 512    // columns (N of the GEMM)

// ---- kernel 1: DCT-III matrix, bf16, Mm[j][k] ----
__global__ void fill_m(u16* __restrict__ Mm) {
  int idx = blockIdx.x * 256 + threadIdx.x;
  if (idx >= NN * NN) return;
  int j = idx >> 10;
  int k = idx & (NN - 1);
  float v;
  if (k == 0) {
    v = 0.03125f;  // 1/sqrt(1024)
  } else {
    int p = (k * (2 * j + 1)) & 4095;              // phase mod 4096 (cos period)
    float ang = (float)p * 1.5339807878856412e-3f; // pi/2048
    v = 0.04419417382415922f * cosf(ang);          // sqrt(2/1024) * cos
  }
  Mm[idx] = f2bf(v);
}

// ---- kernel 2: fused 256x256x(BK=64) 8-wave GEMM, B transposed+converted in-kernel ----
// C[b] = Mm * X[b].  A = Mm[j][k] (bf16, k-contig);  X = x[b][k][c] (f32, c-contig).
// A: XOR-swizzle f_A(r)=r&7 via pre-swizzled global source + linear global_load_lds.
// B: reg-staged (8x float4 = 4c x 8k per thread), cvt, 4x transposing ds_write_b128
//    with DUAL-BIJECTIVE swizzle f(c) = (c ^ (c>>2)) & 7: bijective over c-step-1
//    (frag-read beats) AND c-step-4 (transpose-write beats) -> both sides conflict-free.
// XCD co-schedule: the 4 tm-blocks sharing a (tn,b) B-panel get the same wg&7 -> same
// XCD L2 -> panel fetched once per XCD.
// Tile t read from buf[t&1]; all staging for t+1 targets buf[~t&1].
// Phases q=0..3 (C-quadrant q), barrier each phase end:
//   q0: issue 4 A-gloads(t+1) + 8 B-f32 reg loads(t+1); B-frags(8) + A-frags(q0); 16 MFMA
//   q1: A-frags(q1); 16 MFMA
//   q2: A-frags(q2); 16 MFMA; cvt+4 ds_write (compiler vmcnt drains B regs & A gloads)
//   q3: A-frags(q3); 16 MFMA; lgkmcnt(0)+vmcnt(0) (both ~drained); barrier -> t+1 ready
__global__ __launch_bounds__(512, 2) void gemm_idct(const u16* __restrict__ A,
                                                    const float* __restrict__ X,
                                                    float* __restrict__ C) {
  __shared__ __align__(16) u16 sA[2][16384];  // 64 KiB
  __shared__ __align__(16) u16 sB[2][16384];  // 64 KiB
  // --- XCD-aware block decode: sharers of a B-panel co-land on one XCD ---
  const int wg   = blockIdx.x;
  const int xcd  = wg & 7;
  const int slot = wg >> 3;
  const int tm   = slot & 3;                   // M tile (j), 0..3
  const int pairId = ((slot >> 2) << 3) | xcd; // 0..63
  const int tn   = pairId & 1;                 // N tile (c), 0..1
  const int b    = pairId >> 1;                // batch 0..31

  const int t512 = threadIdx.x;
  const int wave = t512 >> 6, lane = t512 & 63;
  const int wm = wave >> 2, wn = wave & 3;   // 2 x 4 waves; per-wave out 128x64
  const int lhi = lane >> 4, llo = lane & 15;

  // --- A staging map (pre-swizzled source, linear gload_lds dest) ---
  const int srow = t512 >> 3;                  // row-in-slice 0..63
  const int sdc  = (t512 & 7) ^ (srow & 7);    // pre-swizzled data chunk
  const u16* gA = A + (size_t)(tm * 256 + srow) * NN + sdc * 8;
#define ISSUE_A(buf, q, tt) GLOAD_LDS16(gA + (size_t)(q) * 64 * NN + (tt) * 64, \
                                        &sA[buf][(q) * 4096 + t512 * 8])

  // --- B staging map: thread owns c-quad qi*4..qi*4+3 x k-rows kg*8..kg*8+7 ---
  const int qi = ((wave & 3) << 4) | llo;      // 0..63  (c-quad)
  const int kg = ((wave >> 2) << 2) | lhi;     // 0..7   (k-group)
  const float* gX = X + ((size_t)b * NN + kg * 8) * MM + tn * 256 + qi * 4;

  float bA[4][4], bB[4][4];  // [i: k-offset][j: c-offset]

#define LOAD_B_REGS(gptr)                                                   \
  do {                                                                      \
    _Pragma("unroll") for (int i = 0; i < 4; ++i) {                         \
      const float4 v = *(const float4*)((gptr) + (size_t)i * MM);           \
      bA[i][0] = v.x; bA[i][1] = v.y; bA[i][2] = v.z; bA[i][3] = v.w;       \
    }                                                                       \
    _Pragma("unroll") for (int i = 0; i < 4; ++i) {                         \
      const float4 v = *(const float4*)((gptr) + (size_t)(4 + i) * MM);     \
      bB[i][0] = v.x; bB[i][1] = v.y; bB[i][2] = v.z; bB[i][3] = v.w;       \
    }                                                                       \
  } while (0)

#define CVT_WRITE_B(buf)                                                    \
  do {                                                                      \
    _Pragma("unroll") for (int j = 0; j < 4; ++j) {                         \
      const int c = qi * 4 + j;                                             \
      bf16x8 ov;                                                            \
      _Pragma("unroll") for (int i = 0; i < 4; ++i) {                       \
        ov[i] = (__bf16)bA[i][j]; ov[4 + i] = (__bf16)bB[i][j];             \
      }                                                                     \
      const int fc = (c ^ (c >> 2)) & 7;                                    \
      *(bf16x8*)&sB[buf][c * 64 + ((kg ^ fc) << 3)] = ov;                   \
    }                                                                       \
  } while (0)

  // ---- prologue: stage tile 0 into buf 0 ----
  {
#pragma unroll
    for (int q = 0; q < 4; ++q) ISSUE_A(0, q, 0);
    LOAD_B_REGS(gX);
    CVT_WRITE_B(0);
    asm volatile("s_waitcnt vmcnt(0) lgkmcnt(0)" ::: "memory");
    __builtin_amdgcn_s_barrier();
    __builtin_amdgcn_sched_barrier(0);
  }

  f32x4 acc[8][4] = {};
  bf16x8 bfr[4][2];

  for (int t = 0; t < 16; ++t) {
    const int cur = t & 1, nxt = cur ^ 1;
    const u16* lA = &sA[cur][0];
    const u16* lB = &sB[cur][0];
    const float* gXt = gX + (size_t)(t + 1) * 64 * MM;
#pragma unroll
    for (int q = 0; q < 4; ++q) {
      // --- staging issues for tile t+1 (all at q0; land in buf nxt / regs) ---
      if (q == 0 && t < 15) {
#pragma unroll
        for (int s = 0; s < 4; ++s) ISSUE_A(nxt, s, t + 1);
        LOAD_B_REGS(gXt);
      }
      // --- register fragments from buf cur ---
      if (q == 0) {
#pragma unroll
        for (int nf = 0; nf < 4; ++nf)
#pragma unroll
          for (int ks = 0; ks < 2; ++ks) {
            const int rb = wn * 64 + nf * 16 + llo;
            const int fb = (rb ^ (rb >> 2)) & 7;
            bfr[nf][ks] = *(const bf16x8*)&lB[rb * 64 + ((((ks << 2) | lhi) ^ fb) << 3)];
          }
      }
      bf16x8 af[2][2];
#pragma unroll
      for (int mf = 0; mf < 2; ++mf)
#pragma unroll
        for (int ks = 0; ks < 2; ++ks) {
          const int ra = q * 64 + wm * 32 + mf * 16 + llo;
          af[mf][ks] = *(const bf16x8*)&lA[ra * 64 + (((ks << 2) | lhi) ^ (llo & 7)) * 8];
        }
      // --- 16 MFMA (quadrant q x K=64); ks OUTER so same-acc distance = 8 ---
      __builtin_amdgcn_s_setprio(1);
#pragma unroll
      for (int ks = 0; ks < 2; ++ks)
#pragma unroll
        for (int mf = 0; mf < 2; ++mf)
#pragma unroll
          for (int nf = 0; nf < 4; ++nf)
            acc[(q << 1) | mf][nf] = __builtin_amdgcn_mfma_f32_16x16x32_bf16(
                af[mf][ks], bfr[nf][ks], acc[(q << 1) | mf][nf], 0, 0, 0);
      __builtin_amdgcn_s_setprio(0);
      // --- q2: convert + swizzled transposing LDS write of B(t+1) ---
      if (q == 2 && t < 15) CVT_WRITE_B(nxt);
      // --- q3: tile-end drain (both counters already ~drained) ---
      if (q == 3) asm volatile("s_waitcnt vmcnt(0) lgkmcnt(0)" ::: "memory");
      __builtin_amdgcn_sched_barrier(0);
      __builtin_amdgcn_s_barrier();
      __builtin_amdgcn_sched_barrier(0);
    }
  }

  // ---- epilogue: C/D layout col=lane&15, row=(lane>>4)*4+reg ----
  float* Cb = C + (size_t)b * NN * MM;
  const int jbase = tm * 256 + wm * 32 + lhi * 4;
  const int cbase = tn * 256 + wn * 64 + llo;
#pragma unroll
  for (int q = 0; q < 4; ++q)
#pragma unroll
    for (int mf = 0; mf < 2; ++mf)
#pragma unroll
      for (int nf = 0; nf < 4; ++nf) {
        const int j = jbase + q * 64 + mf * 16;
        const int c = cbase + nf * 16;
#pragma unroll
        for (int r = 0; r < 4; ++r)
          Cb[(size_t)(j + r) * MM + c] = acc[(q << 1) | mf][nf][r];
      }
#undef ISSUE_A
#undef LOAD_B_REGS
#undef CVT_WRITE_B
}

extern "C" void kernel_launch(void* const* d_in, const int* in_sizes, int n_in,
                              void* d_out, int out_size, void* d_ws, size_t ws_size,
                              hipStream_t stream) {
  const float* x = (const float*)d_in[0];
  float* out = (float*)d_out;
  u16* Mm = (u16*)d_ws;  // NN*NN u16 = 2 MiB

  fill_m<<<dim3((NN * NN) / 256), dim3(256), 0, stream>>>(Mm);
  gemm_idct<<<dim3(256), dim3(512), 0, stream>>>(Mm, x, out);
}